// Round 4
// baseline (99.287 us; speedup 1.0000x reference)
//
#include <hip/hip_runtime.h>
#include <math.h>

#define BSZ 128
#define T   512
#define E   128
#define H   128

typedef unsigned long long u64;

// Split-fused kernel: 2 blocks per batch row (grid=256, 512 thr = 8 waves each;
// one block per CU -> full-chip BW for the enc read, vs round-3's 128 blocks).
//
// loss = sum_b sum_{m=3}^{len_b-1} [ LSE_{k=m}^{len_b-1} cterm[b,k] - cterm[b,m] ]
//        / sum_b (len_b - 3),  cterm[b,k] = dot(enc[b,k,:], fc_w[H:]).
// (LSTM hidden term and fc_b cancel between lse and pos.)
//
// Row b split at mid=(len+4)/2: block b (role=0, upper, producer) owns rows
// [mid,len); block b+128 (role=1, lower, consumer) owns [3,mid). Upper publishes
// (M_up, E_up=sum exp(c-M_up)) as ONE packed u64 atomicExch into memset-zeroed
// ws; lower spins on it (any valid pack is nonzero: M=-inf => 0xFF800000 bits;
// cnt>0 => E>=1). Lower folds tailX = E_up*exp(M_up-M_lo) into its suffix-LSE —
// max-subtract numerics preserved. Producers are blockIdx 0..127 (scheduled
// first); consumers never block producers -> no deadlock cycle; 2048 waves
// total = 25% capacity, all co-resident.
//
// ws (first 2048 B memset to 0 each call — measured free in rounds 0-3):
//   [0..16)  double accum[2] {loss_sum, pair_count}
//   [16]     int scan_done (256 arrivals; last finalizes out)
//   [32+8b)  u64 pub[b] (packed M_up,E_up; 0 = not ready)

__global__ __launch_bounds__(512) void dli_split_kernel(
    const float* __restrict__ enc,    // [B*T, E]
    const int*   __restrict__ mask,   // [B*T]
    const float* __restrict__ fc_w,   // [H+E]
    double*      __restrict__ accum,
    int*         __restrict__ scan_done,
    u64*         __restrict__ pub,
    float*       __restrict__ out)
{
    const int b    = blockIdx.x & (BSZ - 1);
    const int role = blockIdx.x >> 7;        // 0=upper(producer), 1=lower(consumer)
    const int t    = threadIdx.x;
    const int lane = t & 63;
    const int wid  = t >> 6;                 // wave 0..7
    const int hw   = t >> 5;                 // half-wave 0..15
    const int li   = t & 31;

    __shared__ float s_c[256];               // this half's cterms (cnt <= 255)
    __shared__ float s_red[8];
    __shared__ float s_red2[8];
    __shared__ int   s_lw[8];
    __shared__ float s_sc[2];                // [0]=M_local, [1]=tailX

    // ---- length of row b (both blocks of the pair compute it; mask L2-hot) ----
    const int mv = mask[b * T + t];
    u64 bal = __ballot(mv != 0);
    if (lane == 0) s_lw[wid] = __popcll(bal);
    __syncthreads();                                     // B1
    int len = 0;
    #pragma unroll
    for (int i = 0; i < 8; ++i) len += s_lw[i];          // len in [4,512]

    const int mid = (len + 4) >> 1;          // lower [3,mid) cnt<=255, upper [mid,len) cnt<=255
    const int lo  = role ? 3   : mid;
    const int hi  = role ? mid : len;
    const int cnt = hi - lo;                 // lower >=1; upper may be 0 (len=4)

    // ---- dot: s_c[i] = dot(enc[b, lo+i, :], w_e), half-wave per row ----
    const float4 w4 = *reinterpret_cast<const float4*>(fc_w + H + 4 * li);
    const float* ebase = enc + ((long)b * T + lo) * E;
    #pragma unroll 4
    for (int i = hw; i < cnt; i += 16) {
        const float4 v = *reinterpret_cast<const float4*>(ebase + (long)i * E + 4 * li);
        float p = v.x * w4.x + v.y * w4.y + v.z * w4.z + v.w * w4.w;
        #pragma unroll
        for (int off = 16; off >= 1; off >>= 1) p += __shfl_xor(p, off);
        if (li == 0) s_c[i] = p;
    }
    __syncthreads();                                     // B2

    // ---- local max over this half's cnt elements (thread t owns element t) ----
    float mval = (t < cnt) ? s_c[t] : -INFINITY;
    #pragma unroll
    for (int off = 32; off >= 1; off >>= 1)
        mval = fmaxf(mval, __shfl_xor(mval, off));
    if (lane == 0) s_red[wid] = mval;
    __syncthreads();                                     // B3
    if (t == 0) {
        float m = s_red[0];
        #pragma unroll
        for (int i = 1; i < 8; ++i) m = fmaxf(m, s_red[i]);
        s_sc[0] = m;                         // -inf iff cnt==0 (upper, len==4)
    }
    __syncthreads();                                     // B4
    const float M = s_sc[0];

    // ---- exp + wave-segmented inclusive suffix sum ----
    float x = (t < cnt) ? expf(s_c[t] - M) : 0.0f;
    #pragma unroll
    for (int off = 1; off < 64; off <<= 1) {
        float y = __shfl_down(x, off);
        if (lane + off < 64) x += y;
    }
    if (lane == 0) s_red2[wid] = x;          // per-wave totals
    __syncthreads();                                     // B5

    // ---- handshake: upper publishes (M,E); lower folds it into tailX ----
    if (t == 0) {
        if (role == 0) {
            float Etot = 0.0f;
            #pragma unroll
            for (int i = 0; i < 8; ++i) Etot += s_red2[i];
            u64 u = ((u64)__float_as_uint(M) << 32) | (u64)__float_as_uint(Etot);
            atomicExch(&pub[b], u);          // device-scope; single-word release
            s_sc[1] = 0.0f;
        } else {
            u64 u;
            do { u = atomicAdd(&pub[b], 0ULL); } while (u == 0ULL);
            float Mu = __uint_as_float((unsigned)(u >> 32));
            float Eu = __uint_as_float((unsigned)(u & 0xFFFFFFFFu));
            s_sc[1] = Eu * expf(Mu - M);     // cnt==0 upper: 0*exp(-inf)=0, no NaN
        }
    }
    __syncthreads();                                     // B6
    const float tailX = s_sc[1];

    // ---- per-m terms: M + log(suffix + later-wave totals + tailX) - c_m ----
    float term = 0.0f;
    if (t < cnt) {
        float tail = tailX;
        for (int w = wid + 1; w < 8; ++w) tail += s_red2[w];
        term = M + logf(x + tail) - s_c[t];
    }
    #pragma unroll
    for (int off = 32; off >= 1; off >>= 1)
        term += __shfl_xor(term, off);
    if (lane == 0) s_red[wid] = term;
    __syncthreads();                                     // B7

    if (t == 0) {
        float rs = 0.0f;
        #pragma unroll
        for (int i = 0; i < 8; ++i) rs += s_red[i];
        atomicAdd(&accum[0], (double)rs);
        atomicAdd(&accum[1], (double)cnt);   // lower adds mid-3, upper len-mid
        __threadfence();                     // order accum adds before arrival
        int old = atomicAdd(scan_done, 1);
        if (old == 2 * BSZ - 1) {            // last of 256 blocks finalizes
            __threadfence();                 // acquire others' accum adds
            double a0 = atomicAdd(&accum[0], 0.0);
            double a1 = atomicAdd(&accum[1], 0.0);
            out[0] = (float)(a0 / a1);
        }
    }
}

extern "C" void kernel_launch(void* const* d_in, const int* in_sizes, int n_in,
                              void* d_out, int out_size, void* d_ws, size_t ws_size,
                              hipStream_t stream) {
    const float* enc  = (const float*)d_in[0];   // encoder_output [128,512,128] f32
    const int*   mask = (const int*)d_in[1];     // mask [128,512] i32
    const float* fc_w = (const float*)d_in[6];   // fc_w [1,256] f32
    // d_in[2..5] (LSTM weights) and d_in[7] (fc_b) cancel analytically.

    double* accum     = (double*)d_ws;
    int*    scan_done = (int*)((char*)d_ws + 16);
    u64*    pub       = (u64*)((char*)d_ws + 32);

    hipMemsetAsync(d_ws, 0, 2048, stream);       // accum + scan_done + pub[128]

    dli_split_kernel<<<2 * BSZ, 512, 0, stream>>>(enc, mask, fc_w, accum,
                                                  scan_done, pub, (float*)d_out);
}